// Round 17
// baseline (66.945 us; speedup 1.0000x reference)
//
#include <hip/hip_runtime.h>

// ---------- types ----------
typedef __attribute__((ext_vector_type(8))) short bf16x8;
typedef __attribute__((ext_vector_type(4))) float f32x4;

__device__ __forceinline__ short f2bf(float f) {
  unsigned u = __builtin_bit_cast(unsigned, f);
  u += 0x7fffu + ((u >> 16) & 1u);   // round-to-nearest-even
  return (short)(u >> 16);
}

// ---------- layout (16x16x32 fragment-major, verified R5/R11/R15) ----------
// IN=4096, OUT=4096, RANK=1024, GROUP=128, PACK=8
// GEMM: out[n*4096+m] = sum_r W_V(m,r)*S(r) * W_U(r,n)
// A: elem addr = ((mp*32+kt)*8  + i)*512 + lane*8 + e   (i = 16-row frag 0..7)
//   m = mp*128 + i*16 + (lane&15); r = kt*32 + (lane>>4)*8 + e
// B: elem addr = ((np*32+kt)*16 + j)*512 + lane*8 + e   (j = 16-col frag 0..15)
//   n = np*256 + j*16 + (lane&15); r = kt*32 + (lane>>4)*8 + e

// ---------- stage 1: fused dequant (V -> A, U -> B) — verbatim ----------
__global__ __launch_bounds__(256) void dequant_fused(
    const int* __restrict__ qw_V, const int* __restrict__ qz_V,
    const float* __restrict__ sc_V, const float* __restrict__ S,
    short* __restrict__ A,
    const int* __restrict__ qw_U, const int* __restrict__ qz_U,
    const float* __restrict__ sc_U, short* __restrict__ B) {
  const int bid = blockIdx.x;
  if (bid < 2048) {
    const int t    = bid * 256 + threadIdx.x;      // 0..524287
    const int tile = t >> 9;                       // mp*32 + kt
    const int blk  = (t >> 6) & 7;                 // i
    const int lane = t & 63;
    const int m  = (tile >> 5) * 128 + blk * 16 + (lane & 15);
    const int r0 = (tile & 31) * 32 + ((lane >> 4) << 3);
    const int g  = m >> 7;
    const int sh = (m & 7) << 2;
    const int zw = qz_V[(g << 7) + (r0 >> 3)];
    const int*   wq  = qw_V + (m >> 3) * 1024 + r0;
    const float* scp = sc_V + (g << 10) + r0;
    const float* sp  = S + r0;
    bf16x8 res;
#pragma unroll
    for (int e = 0; e < 8; ++e) {
      int q = (wq[e] >> sh) & 15;
      int z = ((zw >> (e << 2)) & 15) + 1;
      res[e] = f2bf((float)(q - z) * scp[e] * sp[e]);
    }
    *(bf16x8*)(A + ((size_t)t << 3)) = res;        // coalesced
  } else {
    const int t    = (bid - 2048) * 256 + threadIdx.x;
    const int tile = t >> 10;                      // np*32 + kt
    const int blk  = (t >> 6) & 15;                // j
    const int lane = t & 63;
    const int n  = (tile >> 5) * 256 + blk * 16 + (lane & 15);
    const int r0 = (tile & 31) * 32 + ((lane >> 4) << 3);
    const int w  = qw_U[(r0 >> 3) * 4096 + n];
    const int g  = r0 >> 7;
    const int zw = qz_U[(g << 9) + (n >> 3)];
    const int z  = ((zw >> ((n & 7) << 2)) & 15) + 1;
    const float s = sc_U[(g << 12) + n];
    bf16x8 res;
#pragma unroll
    for (int e = 0; e < 8; ++e) {
      int q = (w >> (e << 2)) & 15;
      res[e] = f2bf((float)(q - z) * s);
    }
    *(bf16x8*)(B + ((size_t)t << 3)) = res;
  }
}

// ---------- stage 2: ZERO-BARRIER wave-private pipeline ----------
// Block 128x256, 4 waves, wave tile 64(m) x 128(n), acc[4][8] f32x4.
// Each wave: private 3-slot LDS arena (slot = 12 KB: A frags 4 KB + B 8 KB),
// self-paced loop, NO s_barrier anywhere. Reg ping-pong (X/Y) so MFMA(t)
// never waits on reads(t+1). GLL depth 3 (36 outstanding max).
// Ledger: prologue STG(0,1,2); iter t: [t<=28: STG(t+3)]; vmcnt: t<=28 -> 24,
// t==29 -> 12, t==30 -> 0 (tile t+1 landed); ds_read(t+1) -> alt regs;
// 32 MFMA (cur regs); lgkm(0). Slot t%3 overwritten at iter t (reads of tile
// t completed at end of iter t-1 by THIS wave). 144 KB LDS -> 1 block/CU.
#define GLL(g, l)                                                              \
  __builtin_amdgcn_global_load_lds(                                            \
      (const __attribute__((address_space(1))) void*)(g),                      \
      (__attribute__((address_space(3))) void*)(l), 16, 0, 0)

__global__ __launch_bounds__(256, 1) void gemm_nobar(
    const short* __restrict__ A, const short* __restrict__ B,
    float* __restrict__ out) {
  __shared__ __align__(16) char lds[147456];   // 4 waves x 3 slots x 12 KB
  const int tid  = threadIdx.x;          // 0..255
  const int lane = tid & 63;
  const int wid  = tid >> 6;             // 0..3
  const int wm   = wid >> 1;             // 0..1  (64-row half of 128)
  const int wn   = wid & 1;              // 0..1  (128-col half of 256)
  const int bid = ((blockIdx.x & 7) << 6) | (blockIdx.x >> 3);  // T1 bijective
  const int mp = bid >> 4;               // 0..31
  const int np = bid & 15;               // 0..15

  // wave's global fragment bases (wm/wn folded in; per-lane +lane*16B)
  const short* gAp = A + (size_t)mp * 131072 + (size_t)(wm * 4) * 512 + lane * 8;
  const short* gBp = B + (size_t)np * 262144 + (size_t)(wn * 8) * 512 + lane * 8;
  char* const wl = lds + wid * 36864;    // wave-private arena

  // stage tile t into slot t%3: A frags i=0..3, B frags j=0..7 (12 GLL)
#define STG(t) do {                                                            \
    char* s_ = wl + ((t) % 3) * 12288;                                         \
    const short* a_ = gAp + (size_t)(t) * 4096;                                \
    const short* b_ = gBp + (size_t)(t) * 8192;                                \
    GLL(a_,         s_);          GLL(a_ + 512,  s_ + 1024);                   \
    GLL(a_ + 1024,  s_ + 2048);   GLL(a_ + 1536, s_ + 3072);                   \
    GLL(b_,         s_ + 4096);   GLL(b_ + 512,  s_ + 5120);                   \
    GLL(b_ + 1024,  s_ + 6144);   GLL(b_ + 1536, s_ + 7168);                   \
    GLL(b_ + 2048,  s_ + 8192);   GLL(b_ + 2560, s_ + 9216);                   \
    GLL(b_ + 3072,  s_ + 10240);  GLL(b_ + 3584, s_ + 11264);                  \
  } while (0)

  // read tile t's 12 fragments from slot t%3 into named reg sets
#define RD(dA, dB, t) do {                                                     \
    const char* s_ = wl + ((t) % 3) * 12288 + (lane << 4);                     \
    _Pragma("unroll")                                                          \
    for (int i = 0; i < 4; ++i) dA[i] = *(const bf16x8*)(s_ + (i << 10));      \
    _Pragma("unroll")                                                          \
    for (int j = 0; j < 8; ++j) dB[j] = *(const bf16x8*)(s_ + 4096 + (j << 10)); \
  } while (0)

#define MM(aa, bb) do {                                                        \
    _Pragma("unroll")                                                          \
    for (int i = 0; i < 4; ++i)                                                \
      _Pragma("unroll")                                                        \
      for (int j = 0; j < 8; ++j)                                              \
        acc[i][j] = __builtin_amdgcn_mfma_f32_16x16x32_bf16(                   \
            aa[i], bb[j], acc[i][j], 0, 0, 0);                                 \
  } while (0)

  f32x4 acc[4][8];
#pragma unroll
  for (int i = 0; i < 4; ++i)
#pragma unroll
    for (int j = 0; j < 8; ++j) acc[i][j] = f32x4{0.f, 0.f, 0.f, 0.f};

  bf16x8 aX[4], bX[8], aY[4], bY[8];

  // ---- prologue: 3 tiles in flight; tile 0 into X regs ----
  STG(0); STG(1); STG(2);                               // 36 outstanding
  asm volatile("s_waitcnt vmcnt(24)" ::: "memory");     // tile 0 landed
  RD(aX, bX, 0);
  asm volatile("s_waitcnt lgkmcnt(0)" ::: "memory");
  __builtin_amdgcn_sched_barrier(0);

  for (int u = 0; u < 16; ++u) {
    const int t0 = 2 * u;                // even iter: cur = X, alt = Y
    if (t0 <= 28) STG(t0 + 3);
    if (t0 <= 28) asm volatile("s_waitcnt vmcnt(24)" ::: "memory");
    else          asm volatile("s_waitcnt vmcnt(0)"  ::: "memory");  // t0==30
    if (t0 <= 30) RD(aY, bY, t0 + 1);
    MM(aX, bX);
    if (t0 <= 30) {
      asm volatile("s_waitcnt lgkmcnt(0)" ::: "memory");
      __builtin_amdgcn_sched_barrier(0);
    }
    const int t1 = t0 + 1;               // odd iter: cur = Y, alt = X
    if (t1 <= 28) STG(t1 + 3);
    if (t1 <= 28)      asm volatile("s_waitcnt vmcnt(24)" ::: "memory");
    else if (t1 == 29) asm volatile("s_waitcnt vmcnt(12)" ::: "memory");
    if (t1 <= 30) RD(aX, bX, t1 + 1);
    MM(aY, bY);
    if (t1 <= 30) {
      asm volatile("s_waitcnt lgkmcnt(0)" ::: "memory");
      __builtin_amdgcn_sched_barrier(0);
    }
  }

  // epilogue: out[n*4096 + m]; C map (verified): col(n)=lane&15,
  // row(m)=(lane>>4)*4 + reg -> 4 regs = consecutive m -> float4 store
  const int mbase = (mp << 7) + (wm << 6) + ((lane >> 4) << 2);
  const int nbase = (np << 8) + (wn << 7) + (lane & 15);
#pragma unroll
  for (int i = 0; i < 4; ++i)
#pragma unroll
    for (int j = 0; j < 8; ++j)
      *(f32x4*)(out + (size_t)(nbase + j * 16) * 4096 + mbase + i * 16) =
          acc[i][j];
#undef STG
#undef RD
#undef MM
}

// ---------- launcher ----------
// setup_inputs order: 0:x 1:qweight_V 2:qzeros_V 3:scales_V 4:g_idx_V
//                     5:qweight_U 6:qzeros_U 7:scales_U 8:g_idx_U 9:S
extern "C" void kernel_launch(void* const* d_in, const int* in_sizes, int n_in,
                              void* d_out, int out_size, void* d_ws, size_t ws_size,
                              hipStream_t stream) {
  const int*   qw_V = (const int*)d_in[1];
  const int*   qz_V = (const int*)d_in[2];
  const float* sc_V = (const float*)d_in[3];
  const int*   qw_U = (const int*)d_in[5];
  const int*   qz_U = (const int*)d_in[6];
  const float* sc_U = (const float*)d_in[7];
  const float* S    = (const float*)d_in[9];

  short* A = (short*)d_ws;                  // 8 MB fragment-major (V*S)
  short* B = (short*)d_ws + 4096 * 1024;    // 8 MB fragment-major U^T
  float* out = (float*)d_out;

  dequant_fused<<<4096, 256, 0, stream>>>(qw_V, qz_V, sc_V, S, A,
                                          qw_U, qz_U, sc_U, B);
  gemm_nobar<<<512, 256, 0, stream>>>(A, B, out);
}

// Round 18
// 50.091 us; speedup vs baseline: 1.3365x; 1.3365x over previous
//
#include <hip/hip_runtime.h>

// ---------- types ----------
typedef __attribute__((ext_vector_type(8))) short bf16x8;
typedef __attribute__((ext_vector_type(4))) float f32x4;

__device__ __forceinline__ short f2bf(float f) {
  unsigned u = __builtin_bit_cast(unsigned, f);
  u += 0x7fffu + ((u >> 16) & 1u);   // round-to-nearest-even
  return (short)(u >> 16);
}

// ---------- layout (16x16x32 fragment-major, verified R5/R11) ----------
// IN=4096, OUT=4096, RANK=1024, GROUP=128, PACK=8
// GEMM: out[n*4096+m] = sum_r W_V(m,r)*S(r) * W_U(r,n)
// A: elem addr = ((mp*32+kt)*8  + i)*512 + lane*8 + e   (i = 16-row frag 0..7)
//   m = mp*128 + i*16 + (lane&15); r = kt*32 + (lane>>4)*8 + e
// B: elem addr = ((np*32+kt)*16 + j)*512 + lane*8 + e   (j = 16-col frag 0..15)
//   n = np*256 + j*16 + (lane&15); r = kt*32 + (lane>>4)*8 + e
// Each 1 KB block = one MFMA fragment in lane order: GLL copies contiguously,
// ds_read_b128 stride-1 across lanes (conflict-free).

// ---------- stage 1: fused dequant (V -> A, U -> B) ----------
__global__ __launch_bounds__(256) void dequant_fused(
    const int* __restrict__ qw_V, const int* __restrict__ qz_V,
    const float* __restrict__ sc_V, const float* __restrict__ S,
    short* __restrict__ A,
    const int* __restrict__ qw_U, const int* __restrict__ qz_U,
    const float* __restrict__ sc_U, short* __restrict__ B) {
  const int bid = blockIdx.x;
  if (bid < 2048) {
    const int t    = bid * 256 + threadIdx.x;      // 0..524287
    const int tile = t >> 9;                       // mp*32 + kt
    const int blk  = (t >> 6) & 7;                 // i
    const int lane = t & 63;
    const int m  = (tile >> 5) * 128 + blk * 16 + (lane & 15);
    const int r0 = (tile & 31) * 32 + ((lane >> 4) << 3);
    const int g  = m >> 7;
    const int sh = (m & 7) << 2;
    const int zw = qz_V[(g << 7) + (r0 >> 3)];
    const int*   wq  = qw_V + (m >> 3) * 1024 + r0;
    const float* scp = sc_V + (g << 10) + r0;
    const float* sp  = S + r0;
    bf16x8 res;
#pragma unroll
    for (int e = 0; e < 8; ++e) {
      int q = (wq[e] >> sh) & 15;
      int z = ((zw >> (e << 2)) & 15) + 1;
      res[e] = f2bf((float)(q - z) * scp[e] * sp[e]);
    }
    *(bf16x8*)(A + ((size_t)t << 3)) = res;        // coalesced
  } else {
    const int t    = (bid - 2048) * 256 + threadIdx.x;
    const int tile = t >> 10;                      // np*32 + kt
    const int blk  = (t >> 6) & 15;                // j
    const int lane = t & 63;
    const int n  = (tile >> 5) * 256 + blk * 16 + (lane & 15);
    const int r0 = (tile & 31) * 32 + ((lane >> 4) << 3);
    const int w  = qw_U[(r0 >> 3) * 4096 + n];
    const int g  = r0 >> 7;
    const int zw = qz_U[(g << 9) + (n >> 3)];
    const int z  = ((zw >> ((n & 7) << 2)) & 15) + 1;
    const float s = sc_U[(g << 12) + n];
    bf16x8 res;
#pragma unroll
    for (int e = 0; e < 8; ++e) {
      int q = (w >> (e << 2)) & 15;
      res[e] = f2bf((float)(q - z) * s);
    }
    *(bf16x8*)(B + ((size_t)t << 3)) = res;
  }
}

// ---------- stage 2: 128x256, BK=32, 8 waves, 2 blocks/CU (best: R11/R16) ---
// LDS: buf b at b*24576: A tile (8 KB) at +0, B tile (16 KB) at +8192.
// 48 KB total -> 2 blocks/CU co-resident (512 blocks / 256 CU): cross-block
// TLP hides barriers, vmcnt waits, prologue fill, and the fp32 epilogue tail.
// Per K-step: 3 GLL staging, 8 ds_read_b128, 16 MFMA 16x16x32 per wave.
// vmcnt ledger: prologue stages t0,t1 (6 GLL) -> vmcnt(3) = t0 landed.
// Steady iter kt: reads; lgkm(0); BAR (all reads of buf done); STAGE(kt+2)
// into same buf (now safe); 16 MFMA; vmcnt(3) retires tile kt+1; BAR.
// kt==30: no stage, vmcnt(0). kt==31: no stage, no wait.
#define GLL(g, l)                                                              \
  __builtin_amdgcn_global_load_lds(                                            \
      (const __attribute__((address_space(1))) void*)(g),                      \
      (__attribute__((address_space(3))) void*)(l), 16, 0, 0)

__global__ __launch_bounds__(512, 4) void gemm128x256(
    const short* __restrict__ A, const short* __restrict__ B,
    float* __restrict__ out) {
  __shared__ __align__(16) char lds[49152];
  const int tid  = threadIdx.x;          // 0..511
  const int lane = tid & 63;
  const int wid  = tid >> 6;             // 0..7
  const int wm   = wid >> 2;             // 0..1  (64-row half of 128)
  const int wn   = wid & 3;              // 0..3  (64-col quarter of 256)
  const int bid = ((blockIdx.x & 7) << 6) | (blockIdx.x >> 3);  // T1 bijective
  const int mp = bid >> 4;               // 0..31
  const int np = bid & 15;               // 0..15

  // staging sources (per-lane tid*16B); LDS dests wave-uniform
  const short* gAp = A + (size_t)mp * 131072 + tid * 8;  // panel = 32 tiles * 4096 elems
  const short* gBp = B + (size_t)np * 262144 + tid * 8;  // panel = 32 tiles * 8192 elems
  char* const ldsA = lds + (wid << 10);
  char* const ldsB = lds + 8192 + (wid << 10);

#define STAGE(kt) do {                                                         \
    const int bo_ = ((kt) & 1) * 24576;                                        \
    GLL(gAp + (size_t)(kt) * 4096,        ldsA + bo_);                         \
    GLL(gBp + (size_t)(kt) * 8192,        ldsB + bo_);                         \
    GLL(gBp + (size_t)(kt) * 8192 + 4096, ldsB + bo_ + 8192);                  \
  } while (0)

  // fragment read bases
  const char* Ard = lds + (lane << 4);           // + buf + (wm*4+i)*1024
  const char* Brd = lds + 8192 + (lane << 4);    // + buf + (wn*4+j)*1024

  f32x4 acc[4][4];
#pragma unroll
  for (int i = 0; i < 4; ++i)
#pragma unroll
    for (int j = 0; j < 4; ++j) acc[i][j] = f32x4{0.f, 0.f, 0.f, 0.f};

  // ---- prologue ----
  STAGE(0);
  STAGE(1);
  asm volatile("s_waitcnt vmcnt(3)" ::: "memory");
  __builtin_amdgcn_s_barrier();

  for (int kt = 0; kt < 32; ++kt) {
    const int bo = (kt & 1) * 24576;
    bf16x8 a[4], b[4];
#pragma unroll
    for (int i = 0; i < 4; ++i)
      a[i] = *(const bf16x8*)(Ard + bo + ((wm << 2) + i) * 1024);
#pragma unroll
    for (int j = 0; j < 4; ++j)
      b[j] = *(const bf16x8*)(Brd + bo + ((wn << 2) + j) * 1024);
    asm volatile("s_waitcnt lgkmcnt(0)" ::: "memory");
    __builtin_amdgcn_sched_barrier(0);
    __builtin_amdgcn_s_barrier();        // all waves' reads of this buf done
    if (kt < 30) STAGE(kt + 2);          // overwrite now-safe buf
    __builtin_amdgcn_s_setprio(1);
#pragma unroll
    for (int i = 0; i < 4; ++i)
#pragma unroll
      for (int j = 0; j < 4; ++j)
        acc[i][j] = __builtin_amdgcn_mfma_f32_16x16x32_bf16(
            a[i], b[j], acc[i][j], 0, 0, 0);
    __builtin_amdgcn_s_setprio(0);
    if (kt < 30)       asm volatile("s_waitcnt vmcnt(3)" ::: "memory");
    else if (kt == 30) asm volatile("s_waitcnt vmcnt(0)" ::: "memory");
    if (kt < 31) __builtin_amdgcn_s_barrier();   // publish tile kt+1
  }

  // epilogue: out[n*4096 + m]; 4 acc regs = consecutive m -> float4 store
  const int mbase = (mp << 7) + (wm << 6) + ((lane >> 4) << 2);
  const int nbase = (np << 8) + (wn << 6) + (lane & 15);
#pragma unroll
  for (int mi = 0; mi < 4; ++mi)
#pragma unroll
    for (int ni = 0; ni < 4; ++ni)
      *(f32x4*)(out + (size_t)(nbase + ni * 16) * 4096 + mbase + mi * 16) =
          acc[mi][ni];
#undef STAGE
}

// ---------- launcher ----------
// setup_inputs order: 0:x 1:qweight_V 2:qzeros_V 3:scales_V 4:g_idx_V
//                     5:qweight_U 6:qzeros_U 7:scales_U 8:g_idx_U 9:S
extern "C" void kernel_launch(void* const* d_in, const int* in_sizes, int n_in,
                              void* d_out, int out_size, void* d_ws, size_t ws_size,
                              hipStream_t stream) {
  const int*   qw_V = (const int*)d_in[1];
  const int*   qz_V = (const int*)d_in[2];
  const float* sc_V = (const float*)d_in[3];
  const int*   qw_U = (const int*)d_in[5];
  const int*   qz_U = (const int*)d_in[6];
  const float* sc_U = (const float*)d_in[7];
  const float* S    = (const float*)d_in[9];

  short* A = (short*)d_ws;                  // 8 MB fragment-major (V*S)
  short* B = (short*)d_ws + 4096 * 1024;    // 8 MB fragment-major U^T
  float* out = (float*)d_out;

  dequant_fused<<<4096, 256, 0, stream>>>(qw_V, qz_V, sc_V, S, A,
                                          qw_U, qz_U, sc_U, B);
  gemm128x256<<<512, 512, 0, stream>>>(A, B, out);
}